// Round 11
// baseline (106.338 us; speedup 1.0000x reference)
//
#include <hip/hip_runtime.h>
#include <cstdint>

#define B_   32
#define CIN  256
#define COUT 256
#define H_   56
#define W_   56
#define HP   58          // padded spatial dim (pad=1 each side)
#define HW   (H_ * W_)   // 3136

typedef int v4i  __attribute__((ext_vector_type(4)));
typedef int v16i __attribute__((ext_vector_type(16)));

// ==================================================================
// XNOR conv via i8 MFMA: a,w in {+1,-1}; zero-pad = i8 0 (exact).
// ==================================================================

// ---- pack_a8: NCHW fp32 -> padded NHWC i8. A8[b][hh][ww][ci] ----
__global__ __launch_bounds__(256) void pack_a8_kernel(
    const float* __restrict__ x, const float* __restrict__ alpha,
    char* __restrict__ A8) {
  const int w = threadIdx.x & 63;
  const int q = threadIdx.x >> 6;
  const int hh = blockIdx.x * 4 + q;
  const int b = blockIdx.y;
  if (hh >= HP) return;
  char* rowbase = A8 + (size_t)(b * HP + hh) * (HP * 256);
  const uint4 z = make_uint4(0u, 0u, 0u, 0u);
  if (hh == 0 || hh == HP - 1) {           // border row: all zeros
    for (int i = w; i < HP * 16; i += 64) *(uint4*)(rowbase + i * 16) = z;
    return;
  }
  const int h = hh - 1;
  if (w < W_) {
    char* dst = rowbase + (w + 1) * 256;
    const float* xp = x + (size_t)b * CIN * HW + h * W_ + w;
    for (int cw = 0; cw < 16; ++cw) {      // 16B of channels per iter
      uint32_t wd[4];
      #pragma unroll
      for (int u = 0; u < 4; ++u) {
        uint32_t word = 0;
        #pragma unroll
        for (int bb = 0; bb < 4; ++bb) {
          int c = cw * 16 + u * 4 + bb;
          float v = xp[(size_t)c * HW];
          word |= ((v > alpha[c]) ? 0x01u : 0xFFu) << (bb * 8);
        }
        wd[u] = word;
      }
      *(uint4*)(dst + cw * 16) = *(uint4*)wd;
    }
  } else if (w == 56 || w == 57) {         // border pixels ww=0 / ww=57
    char* dst = rowbase + ((w == 56) ? 0 : (HP - 1)) * 256;
    #pragma unroll
    for (int i = 0; i < 16; ++i) *(uint4*)(dst + i * 16) = z;
  }
}

// ---- pack_w8: W in exact B-fragment form (HW-verified, absmax 0) ----
// Wf[((tap*8 + kc)*8 + ng)*64 + lane]: co = ng*32 + (lane&31),
// ci = kc*32 + (lane>>5)*16 + byte j
__global__ __launch_bounds__(256) void pack_w8_kernel(
    const float* __restrict__ wt, v4i* __restrict__ Wf) {
  int id = blockIdx.x * 256 + threadIdx.x;   // 36864 total
  int lane = id & 63;
  int ng = (id >> 6) & 7;
  int kc = (id >> 9) & 7;
  int tap = id >> 12;
  if (tap >= 9) return;
  int kh = tap / 3, kw = tap - kh * 3;
  int co = ng * 32 + (lane & 31);
  int cib = kc * 32 + (lane >> 5) * 16;
  uint32_t wd[4];
  #pragma unroll
  for (int u = 0; u < 4; ++u) {
    uint32_t word = 0;
    #pragma unroll
    for (int bb = 0; bb < 4; ++bb) {
      int ci = cib + u * 4 + bb;
      float v = wt[((size_t)(co * CIN + ci) * 3 + kh) * 3 + kw];
      word |= ((v > 0.0f) ? 0x01u : 0xFFu) << (bb * 8);
    }
    wd[u] = word;
  }
  Wf[id] = *(v4i*)wd;
}

// ---- conv_mfma v8: r10 tile + PINNED 3-stage pipeline ----
// Block: 256 thr / 4 waves. Block tile M128 (4 oh x 32 ow) x N128.
// Wave: M128 x N32; acc[4] v16i = 64 regs. Slab [gr16][rr6][ww34] = 52,224 B.
// Pipeline per batch t=(kc,kw), fenced with sched_barrier(0):
//   [LOADAF t+1 -> other af buf][SGB][MFMA x12 on af/bf t][SGB]
//   [LOADBF t+2 -> just-freed bf buf][SGB]
// -> af latency covered by prev MFMA cluster (~439cy >> 120cy LDS);
//    bf L2 latency covered by one full batch; compiler emits counted
//    vmcnt(3)/partial lgkm (older batch only), never a drain.
// Fill: (gr,c0)-owned shift/mask addressing (no int division).
// Epilogue: stride-268 scr (odd dword stride -> conflict-free writes),
// ohl-pairs -> 4 lgkm drains total.
__global__ __launch_bounds__(256, 3) void conv_mfma_kernel(
    const char* __restrict__ A8, const v4i* __restrict__ Wf,
    float* __restrict__ out) {
  __shared__ alignas(16) char lds[52224];   // [gr16][rr6][ww34] x 16B
  const int tid = threadIdx.x;
  const int lane = tid & 63;
  const int l31 = lane & 31;
  const int hi  = lane >> 5;
  const int wn  = tid >> 6;

  // bid -> XCD-chunked bijective swizzle (1792 = 8*224)
  const int bid = blockIdx.x;
  const int wg  = (bid & 7) * 224 + (bid >> 3);
  const int coh = wg & 1;
  const int owc = (wg >> 1) & 1;
  const int rest = wg >> 2;
  const int ohq = rest % 14;
  const int b   = rest / 14;
  const int oh0 = ohq * 4;
  const int owbase = owc * 32;

  // ---- fill slab: thread owns (gr = tid&15, c0 = tid>>4); all offsets
  // compile-time immediates off two precomputed bases ----
  {
    const char* srcB = A8 + ((size_t)(b * HP + oh0) * HP + owbase) * 256;
    const int gr = tid & 15, c0 = tid >> 4;
    const char* sbase = srcB + c0 * 256 + gr * 16;
    char* dbase = lds + gr * 3264 + c0 * 16;
    #pragma unroll
    for (int rr = 0; rr < 6; ++rr) {
      #pragma unroll
      for (int k = 0; k < 3; ++k) {
        int wwl = k * 16 + c0;
        if (wwl < 34) {
          uint4 v = make_uint4(0u, 0u, 0u, 0u);
          if (owbase + wwl < HP)
            v = *(const uint4*)(sbase + rr * (HP * 256) + k * (16 * 256));
          *(uint4*)(dbase + rr * 544 + k * 256) = v;
        }
      }
    }
  }
  __syncthreads();

  v16i acc[4];
  #pragma unroll
  for (int m = 0; m < 4; ++m)
    #pragma unroll
    for (int e = 0; e < 16; ++e) acc[m][e] = 0;

  // af addr = lds + hi*3264 + (l31+kw)*16 + kc*6528 + rr*544
  int aoff[3];
  #pragma unroll
  for (int kw = 0; kw < 3; ++kw) aoff[kw] = hi * 3264 + (l31 + kw) * 16;
  const char* ab = lds;
  const v4i* wb = Wf + (coh * 4 + wn) * 64 + lane;   // ng = coh*4+wn

#define LOADAF(dst, t) do {                                           \
    const int kc_ = (t) / 3, kw_ = (t) % 3;                           \
    _Pragma("unroll")                                                 \
    for (int rr_ = 0; rr_ < 6; ++rr_)                                 \
      (dst)[rr_] = *(const v4i*)(ab + aoff[kw_] + kc_ * 6528 + rr_ * 544); \
  } while (0)
#define LOADBF(dst, t) do {                                           \
    const int kc_ = (t) / 3, kw_ = (t) % 3;                           \
    _Pragma("unroll")                                                 \
    for (int kh_ = 0; kh_ < 3; ++kh_)                                 \
      (dst)[kh_] = wb[((kh_ * 3 + kw_) * 8 + kc_) * 512];             \
  } while (0)
#define MFMA12(afx, bfx) do {                                         \
    _Pragma("unroll")                                                 \
    for (int kh_ = 0; kh_ < 3; ++kh_)                                 \
      _Pragma("unroll")                                               \
      for (int ohl_ = 0; ohl_ < 4; ++ohl_)                            \
        acc[ohl_] = __builtin_amdgcn_mfma_i32_32x32x32_i8(            \
            (afx)[ohl_ + kh_], (bfx)[kh_], acc[ohl_], 0, 0, 0);       \
  } while (0)
#define SGB __builtin_amdgcn_sched_barrier(0)

  v4i aA[6], aB[6], bA[3], bB[3];
  LOADAF(aA, 0);
  LOADBF(bA, 0);
  LOADBF(bB, 1);

  #pragma unroll
  for (int tt = 0; tt < 12; ++tt) {
    const int t0 = tt * 2, t1 = t0 + 1;
    // even batch: consume aA/bA
    if (t0 + 1 < 24) LOADAF(aB, t0 + 1);
    SGB;
    MFMA12(aA, bA);
    SGB;
    if (t0 + 2 < 24) LOADBF(bA, t0 + 2);
    SGB;
    // odd batch: consume aB/bB
    if (t1 + 1 < 24) LOADAF(aA, t1 + 1);
    SGB;
    MFMA12(aB, bB);
    SGB;
    if (t1 + 2 < 24) LOADBF(bB, t1 + 2);
    SGB;
  }
#undef LOADAF
#undef LOADBF
#undef MFMA12

  // ---- epilogue: transpose via dead slab, ohl-pairs, 4 drains total ----
  __syncthreads();
  char* scr = lds + wn * 13056;      // per-wave region; [co32] stride 268B
  const int co0 = (coh * 4 + wn) * 32;

  #pragma unroll
  for (int pr = 0; pr < 2; ++pr) {
    #pragma unroll
    for (int ohl1 = 0; ohl1 < 2; ++ohl1) {
      const int ohl = pr * 2 + ohl1;
      #pragma unroll
      for (int q = 0; q < 4; ++q) {
        float4 f;
        f.x = (float)acc[ohl][q * 4 + 0];
        f.y = (float)acc[ohl][q * 4 + 1];
        f.z = (float)acc[ohl][q * 4 + 2];
        f.w = (float)acc[ohl][q * 4 + 3];
        // m = q*8 + hi*4 + j -> byte q*32 + hi*16
        *(float4*)(scr + l31 * 268 + ohl1 * 132 + q * 32 + hi * 16) = f;
      }
    }
    asm volatile("s_waitcnt lgkmcnt(0)" ::: "memory");
    SGB;
    #pragma unroll
    for (int ohl1 = 0; ohl1 < 2; ++ohl1) {
      #pragma unroll
      for (int t = 0; t < 4; ++t) {
        int idx = t * 64 + lane;     // 0..255 = co_l*8 + s
        int co_l = idx >> 3;
        int s = idx & 7;
        int ow = owbase + s * 4;
        if (ow + 3 < W_) {           // owc=1 drops s>=6
          float4 v = *(const float4*)(scr + co_l * 268 + ohl1 * 132 + s * 16);
          float* op = out + ((size_t)(b * COUT + co0 + co_l) * H_ +
                             oh0 + pr * 2 + ohl1) * W_ + ow;
          *(float4*)op = v;
        }
      }
    }
    asm volatile("s_waitcnt lgkmcnt(0)" ::: "memory");
    SGB;
  }
#undef SGB
}

// ==================================================================
extern "C" void kernel_launch(void* const* d_in, const int* in_sizes, int n_in,
                              void* d_out, int out_size, void* d_ws, size_t ws_size,
                              hipStream_t stream) {
  const float* x     = (const float*)d_in[0];
  const float* alpha = (const float*)d_in[1];
  const float* wt    = (const float*)d_in[2];
  float* out = (float*)d_out;

  const size_t needA = (size_t)B_ * HP * HP * 256;   // 27,557,888 B
  char* A8 = (char*)d_ws;
  v4i* Wf  = (v4i*)(A8 + needA);

  pack_a8_kernel<<<dim3(15, 32), 256, 0, stream>>>(x, alpha, A8);
  pack_w8_kernel<<<144, 256, 0, stream>>>(wt, Wf);
  conv_mfma_kernel<<<dim3(B_ * 14 * 2 * 2), 256, 0, stream>>>(A8, Wf, out);
}

// Round 12
// 100.177 us; speedup vs baseline: 1.0615x; 1.0615x over previous
//
#include <hip/hip_runtime.h>
#include <cstdint>

#define B_   32
#define CIN  256
#define COUT 256
#define H_   56
#define W_   56
#define HP   58          // padded spatial dim (pad=1 each side)
#define HW   (H_ * W_)   // 3136

typedef int v4i  __attribute__((ext_vector_type(4)));
typedef int v16i __attribute__((ext_vector_type(16)));

// ==================================================================
// XNOR conv via i8 MFMA: a,w in {+1,-1}; zero-pad = i8 0 (exact).
// ==================================================================

// ---- pack_a8: NCHW fp32 -> padded NHWC i8. A8[b][hh][ww][ci] ----
__global__ __launch_bounds__(256) void pack_a8_kernel(
    const float* __restrict__ x, const float* __restrict__ alpha,
    char* __restrict__ A8) {
  const int w = threadIdx.x & 63;
  const int q = threadIdx.x >> 6;
  const int hh = blockIdx.x * 4 + q;
  const int b = blockIdx.y;
  if (hh >= HP) return;
  char* rowbase = A8 + (size_t)(b * HP + hh) * (HP * 256);
  const uint4 z = make_uint4(0u, 0u, 0u, 0u);
  if (hh == 0 || hh == HP - 1) {           // border row: all zeros
    for (int i = w; i < HP * 16; i += 64) *(uint4*)(rowbase + i * 16) = z;
    return;
  }
  const int h = hh - 1;
  if (w < W_) {
    char* dst = rowbase + (w + 1) * 256;
    const float* xp = x + (size_t)b * CIN * HW + h * W_ + w;
    for (int cw = 0; cw < 16; ++cw) {      // 16B of channels per iter
      uint32_t wd[4];
      #pragma unroll
      for (int u = 0; u < 4; ++u) {
        uint32_t word = 0;
        #pragma unroll
        for (int bb = 0; bb < 4; ++bb) {
          int c = cw * 16 + u * 4 + bb;
          float v = xp[(size_t)c * HW];
          word |= ((v > alpha[c]) ? 0x01u : 0xFFu) << (bb * 8);
        }
        wd[u] = word;
      }
      *(uint4*)(dst + cw * 16) = *(uint4*)wd;
    }
  } else if (w == 56 || w == 57) {         // border pixels ww=0 / ww=57
    char* dst = rowbase + ((w == 56) ? 0 : (HP - 1)) * 256;
    #pragma unroll
    for (int i = 0; i < 16; ++i) *(uint4*)(dst + i * 16) = z;
  }
}

// ---- pack_w8: W in exact B-fragment form (HW-verified, absmax 0) ----
// Wf[((tap*8 + kc)*8 + ng)*64 + lane]: co = ng*32 + (lane&31),
// ci = kc*32 + (lane>>5)*16 + byte j
__global__ __launch_bounds__(256) void pack_w8_kernel(
    const float* __restrict__ wt, v4i* __restrict__ Wf) {
  int id = blockIdx.x * 256 + threadIdx.x;   // 36864 total
  int lane = id & 63;
  int ng = (id >> 6) & 7;
  int kc = (id >> 9) & 7;
  int tap = id >> 12;
  if (tap >= 9) return;
  int kh = tap / 3, kw = tap - kh * 3;
  int co = ng * 32 + (lane & 31);
  int cib = kc * 32 + (lane >> 5) * 16;
  uint32_t wd[4];
  #pragma unroll
  for (int u = 0; u < 4; ++u) {
    uint32_t word = 0;
    #pragma unroll
    for (int bb = 0; bb < 4; ++bb) {
      int ci = cib + u * 4 + bb;
      float v = wt[((size_t)(co * CIN + ci) * 3 + kh) * 3 + kw];
      word |= ((v > 0.0f) ? 0x01u : 0xFFu) << (bb * 8);
    }
    wd[u] = word;
  }
  Wf[id] = *(v4i*)wd;
}

// ---- conv_mfma v9: r10 inner loop + kc-split slab -> 4 blocks/CU ----
// Block: 256 thr / 4 waves. Block tile M128 (4 oh x 32 ow) x N128.
// Wave: M128 x N32; acc[4] v16i = 64 regs.
// Slab per PHASE (kc-half): [gr8][rr6][ww34] x 16B = 26,112 B ->
// LDS allows 6 blocks/CU; register target <=128/wave (acc 64 + arch ~60)
// via launch_bounds(256,4) -> 4 blocks/CU = 4 waves/SIMD (was 2.2 avg).
// Two phases: fill(kc 0-3) / compute / barrier / fill(kc 4-7) / compute.
// Inner batch (kcp,kw): 6 af ds_reads + 3 bf L2 loads + 12 MFMAs,
// compiler-scheduled (r11 showed sched_barrier pinning regresses).
__global__ __launch_bounds__(256, 4) void conv_mfma_kernel(
    const char* __restrict__ A8, const v4i* __restrict__ Wf,
    float* __restrict__ out) {
  __shared__ alignas(16) char lds[26112];   // [gr8][rr6][ww34] x 16B
  const int tid = threadIdx.x;
  const int lane = tid & 63;
  const int l31 = lane & 31;
  const int hi  = lane >> 5;
  const int wn  = tid >> 6;

  // bid -> XCD-chunked bijective swizzle (1792 = 8*224)
  const int bid = blockIdx.x;
  const int wg  = (bid & 7) * 224 + (bid >> 3);
  const int coh = wg & 1;
  const int owc = (wg >> 1) & 1;
  const int rest = wg >> 2;
  const int ohq = rest % 14;
  const int b   = rest / 14;
  const int oh0 = ohq * 4;
  const int owbase = owc * 32;

  v16i acc[4];
  #pragma unroll
  for (int m = 0; m < 4; ++m)
    #pragma unroll
    for (int e = 0; e < 16; ++e) acc[m][e] = 0;

  // thread-constant bases; every hot-loop offset is a compile-time imm
  const char* abase = lds + hi * 3264 + l31 * 16;   // + kcp*6528 + rr*544 + kw*16
  const v4i* wb = Wf + (coh * 4 + wn) * 64 + lane;  // ng = coh*4+wn
  const char* srcT = A8 + ((size_t)(b * HP + oh0) * HP + owbase) * 256;

  #pragma unroll
  for (int ph = 0; ph < 2; ++ph) {
    if (ph) __syncthreads();             // all waves done with phase-0 slab
    // ---- fill phase slab: linear i = (gr*6+rr)*34 + wwl ----
    for (int i = tid; i < 1632; i += 256) {
      int gr  = i / 204;                 // ci granule 0..7 (kcp*2+hi)
      int rem = i - gr * 204;
      int rr  = rem / 34;
      int wwl = rem - rr * 34;
      uint4 v = make_uint4(0u, 0u, 0u, 0u);
      if (owbase + wwl < HP)
        v = *(const uint4*)(srcT + ((size_t)rr * HP + wwl) * 256 +
                            ph * 128 + gr * 16);
      *(uint4*)(lds + i * 16) = v;
    }
    __syncthreads();

    #pragma unroll
    for (int kcp = 0; kcp < 4; ++kcp) {
      #pragma unroll
      for (int kw = 0; kw < 3; ++kw) {
        v4i af[6];
        #pragma unroll
        for (int rr = 0; rr < 6; ++rr)
          af[rr] = *(const v4i*)(abase + kcp * 6528 + rr * 544 + kw * 16);
        v4i bf[3];
        #pragma unroll
        for (int kh = 0; kh < 3; ++kh)
          bf[kh] = wb[((kh * 3 + kw) * 8 + ph * 4 + kcp) * 512];
        #pragma unroll
        for (int kh = 0; kh < 3; ++kh)
          #pragma unroll
          for (int ohl = 0; ohl < 4; ++ohl)
            acc[ohl] = __builtin_amdgcn_mfma_i32_32x32x32_i8(
                af[ohl + kh], bf[kh], acc[ohl], 0, 0, 0);
      }
    }
  }

  // ---- epilogue: per-wave transpose via dead slab, row stores ----
  __syncthreads();                   // slab dead for all waves
  char* scr = lds + wn * 4608;       // [co 32] stride 144B x 32 floats
  const int co0 = (coh * 4 + wn) * 32;

  #pragma unroll
  for (int ohl = 0; ohl < 4; ++ohl) {
    #pragma unroll
    for (int q = 0; q < 4; ++q) {
      float4 f;
      f.x = (float)acc[ohl][q * 4 + 0];
      f.y = (float)acc[ohl][q * 4 + 1];
      f.z = (float)acc[ohl][q * 4 + 2];
      f.w = (float)acc[ohl][q * 4 + 3];
      // m = q*8 + hi*4 + j -> byte q*32 + hi*16
      *(float4*)(scr + l31 * 144 + q * 32 + hi * 16) = f;
    }
    asm volatile("s_waitcnt lgkmcnt(0)" ::: "memory");
    __builtin_amdgcn_sched_barrier(0);
    #pragma unroll
    for (int t = 0; t < 4; ++t) {
      int idx = t * 64 + lane;       // 0..255 = co_l*8 + s
      int co_l = idx >> 3;
      int s = idx & 7;
      int ow = owbase + s * 4;
      if (ow + 3 < W_) {             // owc=1 drops s>=6 (garbage cols)
        float4 v = *(const float4*)(scr + co_l * 144 + s * 16);
        float* op = out + ((size_t)(b * COUT + co0 + co_l) * H_ + oh0 + ohl) * W_ + ow;
        *(float4*)op = v;
      }
    }
    asm volatile("s_waitcnt lgkmcnt(0)" ::: "memory");
    __builtin_amdgcn_sched_barrier(0);
  }
}

// ==================================================================
extern "C" void kernel_launch(void* const* d_in, const int* in_sizes, int n_in,
                              void* d_out, int out_size, void* d_ws, size_t ws_size,
                              hipStream_t stream) {
  const float* x     = (const float*)d_in[0];
  const float* alpha = (const float*)d_in[1];
  const float* wt    = (const float*)d_in[2];
  float* out = (float*)d_out;

  const size_t needA = (size_t)B_ * HP * HP * 256;   // 27,557,888 B
  char* A8 = (char*)d_ws;
  v4i* Wf  = (v4i*)(A8 + needA);

  pack_a8_kernel<<<dim3(15, 32), 256, 0, stream>>>(x, alpha, A8);
  pack_w8_kernel<<<144, 256, 0, stream>>>(wt, Wf);
  conv_mfma_kernel<<<dim3(B_ * 14 * 2 * 2), 256, 0, stream>>>(A8, Wf, out);
}